// Round 6
// baseline (2456.889 us; speedup 1.0000x reference)
//
#include <hip/hip_runtime.h>
#include <math.h>

#define B_  4
#define S_  1024
#define D_  2048
#define NL_ 2
#define H_  16
#define KV_ 4
#define F_  8192
#define R_  16
#define HD_ 128
#define BS_ (B_*S_)   // 4096 tokens
#define QT2 32
#define KBLK 64

typedef unsigned short u16;
typedef __attribute__((ext_vector_type(8))) __bf16 bf16x8;
typedef __attribute__((ext_vector_type(4))) float  f32x4;

__device__ __forceinline__ u16 f2bf(float f) {
    unsigned x = __float_as_uint(f);
    unsigned r = (x + 0x7fffu + ((x >> 16) & 1u)) >> 16;   // RNE
    return (u16)r;
}
__device__ __forceinline__ float bf2f(u16 u) {
    return __uint_as_float(((unsigned)u) << 16);
}

// async global->LDS, 16B per lane. LDS dest must be linear (base + lane*16).
__device__ __forceinline__ void gload16(const void* g, void* l) {
    __builtin_amdgcn_global_load_lds((const __attribute__((address_space(1))) void*)g,
                                     (__attribute__((address_space(3))) void*)l, 16, 0, 0);
}

// ------------------------------------------------------------------
__global__ void embed_kernel(const float* __restrict__ embed,
                             const int* __restrict__ ids,
                             float* __restrict__ x) {
    int tok = blockIdx.x;
    int id  = ids[tok];
    const float4* src = (const float4*)(embed + (size_t)id * D_);
    float4*       dst = (float4*)(x + (size_t)tok * D_);
    for (int i = threadIdx.x; i < D_/4; i += blockDim.x) dst[i] = src[i];
}

// ------------------------------------------------------------------
template<int OUTBF>
__global__ __launch_bounds__(256) void rmsnorm_kernel(const float* __restrict__ x,
                                                      const float* __restrict__ w,
                                                      void* __restrict__ out) {
    int row = blockIdx.x;
    const float4* xr = (const float4*)(x + (size_t)row * D_);
    float ss = 0.f;
    for (int i = threadIdx.x; i < D_/4; i += 256) {
        float4 v = xr[i];
        ss += v.x*v.x + v.y*v.y + v.z*v.z + v.w*v.w;
    }
    __shared__ float red[4];
    for (int off = 32; off; off >>= 1) ss += __shfl_down(ss, off);
    if ((threadIdx.x & 63) == 0) red[threadIdx.x >> 6] = ss;
    __syncthreads();
    float tot = red[0] + red[1] + red[2] + red[3];
    float scale = rsqrtf(tot / (float)D_ + 1e-5f);
    const float4* w4 = (const float4*)w;
    for (int i = threadIdx.x; i < D_/4; i += 256) {
        float4 v = xr[i], g = w4[i];
        float a = v.x*scale*g.x, b = v.y*scale*g.y, c = v.z*scale*g.z, d = v.w*scale*g.w;
        if (OUTBF) {
            ushort4 o; o.x = f2bf(a); o.y = f2bf(b); o.z = f2bf(c); o.w = f2bf(d);
            ((ushort4*)((u16*)out + (size_t)row * D_))[i] = o;
        } else {
            float4 o; o.x = a; o.y = b; o.z = c; o.w = d;
            ((float4*)((float*)out + (size_t)row * D_))[i] = o;
        }
    }
}

// ------------------------------------------------------------------
// transpose + f32->bf16: in [K][N] f32 row-major  ->  out [N][K] bf16 row-major
__global__ __launch_bounds__(256) void convt_kernel(const float* __restrict__ in,
                                                    u16* __restrict__ outT,
                                                    int K, int N) {
    __shared__ float tile[32][33];
    int k0 = blockIdx.y * 32, n0 = blockIdx.x * 32;
    int t = threadIdx.x;
    int r = t >> 3, c4 = (t & 7) * 4;
    float4 v = *(const float4*)(in + (size_t)(k0 + r) * N + n0 + c4);
    tile[r][c4] = v.x; tile[r][c4+1] = v.y; tile[r][c4+2] = v.z; tile[r][c4+3] = v.w;
    __syncthreads();
    int n = t >> 3, kc = (t & 7) * 4;
    ushort4 o;
    o.x = f2bf(tile[kc][n]);   o.y = f2bf(tile[kc+1][n]);
    o.z = f2bf(tile[kc+2][n]); o.w = f2bf(tile[kc+3][n]);
    *(ushort4*)(outT + (size_t)(n0 + n) * K + k0 + kc) = o;
}

// ------------------------------------------------------------------
// MFMA GEMM, B transposed: C[M,N] (+)= A[M,K](bf16) @ Bt[N,K](bf16)^T, C f32
template<int ACC>
__global__ __launch_bounds__(256) void gemm_bt(const u16* __restrict__ A,
                                               const u16* __restrict__ Bt,
                                               float* __restrict__ C,
                                               int N, int K) {
    __shared__ __align__(16) u16 As[128*64];
    __shared__ __align__(16) u16 Bs[128*64];
    int tid = threadIdx.x, lane = tid & 63;
    int wid = tid >> 6, wm = wid >> 1, wn = wid & 1;
    int m0 = blockIdx.y * 128, n0 = blockIdx.x * 128;
    const u16* Ab = A  + (size_t)m0 * K;
    const u16* Bb = Bt + (size_t)n0 * K;
    f32x4 acc[4][4] = {};
    for (int k0 = 0; k0 < K; k0 += 64) {
        #pragma unroll
        for (int qq = 0; qq < 4; qq++) {
            int u = qq * 256 + tid;
            int row = u >> 3, cu = u & 7, scu = cu ^ (row & 7);
            size_t goff = (size_t)row * K + k0 + scu * 8;
            gload16(Ab + goff, (char*)As + u * 16);
            gload16(Bb + goff, (char*)Bs + u * 16);
        }
        __syncthreads();
        #pragma unroll
        for (int kk = 0; kk < 2; kk++) {
            int cu = kk * 4 + (lane >> 4);
            bf16x8 af[4], bfr[4];
            #pragma unroll
            for (int i = 0; i < 4; i++) {
                int ar = wm * 64 + i * 16 + (lane & 15);
                af[i]  = *(const bf16x8*)((const char*)As + (((ar << 3) | (cu ^ (ar & 7))) << 4));
                int br = wn * 64 + i * 16 + (lane & 15);
                bfr[i] = *(const bf16x8*)((const char*)Bs + (((br << 3) | (cu ^ (br & 7))) << 4));
            }
            #pragma unroll
            for (int i = 0; i < 4; i++)
                #pragma unroll
                for (int j = 0; j < 4; j++)
                    acc[i][j] = __builtin_amdgcn_mfma_f32_16x16x32_bf16(af[i], bfr[j], acc[i][j], 0, 0, 0);
        }
        __syncthreads();
    }
    int r0 = (lane >> 4) * 4, c0 = lane & 15;
    #pragma unroll
    for (int i = 0; i < 4; i++)
        #pragma unroll
        for (int j = 0; j < 4; j++) {
            int row = m0 + wm * 64 + i * 16 + r0;
            int col = n0 + wn * 64 + j * 16 + c0;
            float* cp = C + (size_t)row * N + col;
            #pragma unroll
            for (int r = 0; r < 4; r++) {
                if (ACC) cp[(size_t)r * N] += acc[i][j][r];
                else     cp[(size_t)r * N] = acc[i][j][r];
            }
        }
}

// ------------------------------------------------------------------
// fused gate/up MFMA GEMM: act = silu(A@G) * (A@U)
// 128x128 tile per operand, BK=64, 4 waves (2x2), wave tile 64x64 each.
__global__ __launch_bounds__(256) void gemm_gateup_bt(const u16* __restrict__ A,
                                                      const u16* __restrict__ Gt,
                                                      const u16* __restrict__ Ut,
                                                      u16* __restrict__ act,
                                                      int N, int K) {
    __shared__ __align__(16) u16 As[128*64];
    __shared__ __align__(16) u16 Gs[128*64];
    __shared__ __align__(16) u16 Us[128*64];
    int tid = threadIdx.x, lane = tid & 63;
    int wid = tid >> 6, wm = wid >> 1, wn = wid & 1;
    int m0 = blockIdx.y * 128, n0 = blockIdx.x * 128;
    const u16* Ab = A  + (size_t)m0 * K;
    const u16* Gb = Gt + (size_t)n0 * K;
    const u16* Ub = Ut + (size_t)n0 * K;
    f32x4 ag[4][4] = {}, au[4][4] = {};
    for (int k0 = 0; k0 < K; k0 += 64) {
        #pragma unroll
        for (int qq = 0; qq < 4; qq++) {
            int u = qq * 256 + tid;
            int row = u >> 3, cu = u & 7, scu = cu ^ (row & 7);
            size_t goff = (size_t)row * K + k0 + scu * 8;
            gload16(Ab + goff, (char*)As + u * 16);
            gload16(Gb + goff, (char*)Gs + u * 16);
            gload16(Ub + goff, (char*)Us + u * 16);
        }
        __syncthreads();
        #pragma unroll
        for (int kk = 0; kk < 2; kk++) {
            int cu = kk * 4 + (lane >> 4);
            bf16x8 af[4], gf[4], uf[4];
            #pragma unroll
            for (int i = 0; i < 4; i++) {
                int ar = wm * 64 + i * 16 + (lane & 15);
                af[i] = *(const bf16x8*)((const char*)As + (((ar << 3) | (cu ^ (ar & 7))) << 4));
            }
            #pragma unroll
            for (int j = 0; j < 4; j++) {
                int br = wn * 64 + j * 16 + (lane & 15);
                int off = ((br << 3) | (cu ^ (br & 7))) << 4;
                gf[j] = *(const bf16x8*)((const char*)Gs + off);
                uf[j] = *(const bf16x8*)((const char*)Us + off);
            }
            #pragma unroll
            for (int i = 0; i < 4; i++)
                #pragma unroll
                for (int j = 0; j < 4; j++) {
                    ag[i][j] = __builtin_amdgcn_mfma_f32_16x16x32_bf16(af[i], gf[j], ag[i][j], 0, 0, 0);
                    au[i][j] = __builtin_amdgcn_mfma_f32_16x16x32_bf16(af[i], uf[j], au[i][j], 0, 0, 0);
                }
        }
        __syncthreads();
    }
    int r0 = (lane >> 4) * 4, c0 = lane & 15;
    #pragma unroll
    for (int i = 0; i < 4; i++)
        #pragma unroll
        for (int j = 0; j < 4; j++) {
            int col = n0 + wn * 64 + j * 16 + c0;
            #pragma unroll
            for (int r = 0; r < 4; r++) {
                int row = m0 + wm * 64 + i * 16 + r0 + r;
                float g = ag[i][j][r], u = au[i][j][r];
                float s = g / (1.f + __expf(-g));
                act[(size_t)row * N + col] = f2bf(s * u);
            }
        }
}

// ------------------------------------------------------------------
// LoRA
__global__ __launch_bounds__(256) void lora_a_kernel(const u16* __restrict__ h,
                                                     const float* __restrict__ la,
                                                     float* __restrict__ t16) {
    int r = threadIdx.x >> 4;
    int c = threadIdx.x & 15;
    int row = blockIdx.x * 16 + r;
    const ushort4* hr = (const ushort4*)(h + (size_t)row * D_);
    const float4* lr = (const float4*)(la + (size_t)c * D_);
    float acc = 0.f;
    #pragma unroll 4
    for (int i = 0; i < D_/4; i++) {
        ushort4 a = hr[i]; float4 b = lr[i];
        acc += bf2f(a.x)*b.x + bf2f(a.y)*b.y + bf2f(a.z)*b.z + bf2f(a.w)*b.w;
    }
    t16[(size_t)row * R_ + c] = acc;
}

__global__ __launch_bounds__(256) void lora_b_kernel(const float* __restrict__ t16,
                                                     const float* __restrict__ lb,
                                                     float* __restrict__ out, int N) {
    int row = blockIdx.x;
    __shared__ float ts[R_];
    if (threadIdx.x < R_) ts[threadIdx.x] = t16[(size_t)row * R_ + threadIdx.x];
    __syncthreads();
    for (int d = threadIdx.x; d < N; d += 256) {
        const float4* lbr = (const float4*)(lb + (size_t)d * R_);
        float acc = 0.f;
        #pragma unroll
        for (int r4 = 0; r4 < 4; r4++) {
            float4 v = lbr[r4];
            acc += v.x*ts[r4*4] + v.y*ts[r4*4+1] + v.z*ts[r4*4+2] + v.w*ts[r4*4+3];
        }
        out[(size_t)row * N + d] += 2.0f * acc;
    }
}

// ------------------------------------------------------------------
// fused RoPE + f32->bf16 conv, Q: [BS,H,128] f32 -> Qc [B][H][S][128] bf16
__global__ void qconv_rope(const float* __restrict__ q, u16* __restrict__ Qc) {
    int tok = blockIdx.x, h = blockIdx.y, t = threadIdx.x;   // t: 0..63
    int b = tok >> 10, s = tok & (S_ - 1);
    float inv = __expf(-(float)t * (13.122363377404328f / 64.0f));
    float f = (float)s * inv;
    float c = __cosf(f), si = __sinf(f);
    const float* src = q + ((size_t)tok * H_ + h) * HD_;
    float x0 = src[t], x1 = src[t + 64];
    u16* dst = Qc + (((size_t)(b * H_ + h)) * S_ + s) * HD_;
    dst[t]      = f2bf(x0 * c - x1 * si);
    dst[t + 64] = f2bf(x1 * c + x0 * si);
}

// K: [BS,KV,128] f32 -> Kc [B][KV][S][128] bf16 (with RoPE)
__global__ void kconv_rope(const float* __restrict__ k, u16* __restrict__ Kc) {
    int tok = blockIdx.x, h = blockIdx.y, t = threadIdx.x;
    int b = tok >> 10, s = tok & (S_ - 1);
    float inv = __expf(-(float)t * (13.122363377404328f / 64.0f));
    float f = (float)s * inv;
    float c = __cosf(f), si = __sinf(f);
    const float* src = k + ((size_t)tok * KV_ + h) * HD_;
    float x0 = src[t], x1 = src[t + 64];
    u16* dst = Kc + (((size_t)(b * KV_ + h)) * S_ + s) * HD_;
    dst[t]      = f2bf(x0 * c - x1 * si);
    dst[t + 64] = f2bf(x1 * c + x0 * si);
}

// V: [BS,KV,128] f32 -> Vt [B][KV][128][S] bf16 (transposed)
__global__ __launch_bounds__(256) void vconv_t(const float* __restrict__ vb,
                                               u16* __restrict__ Vt) {
    __shared__ float tile[32][33];
    int s0 = blockIdx.x * 32, d0 = blockIdx.y * 32;
    int bk = blockIdx.z;
    int b = bk >> 2, kvh = bk & 3;
    int t = threadIdx.x;
    int r = t >> 3, c4 = (t & 7) * 4;
    float4 v = *(const float4*)(vb + (((size_t)(b * S_ + s0 + r)) * KV_ + kvh) * HD_ + d0 + c4);
    tile[r][c4] = v.x; tile[r][c4+1] = v.y; tile[r][c4+2] = v.z; tile[r][c4+3] = v.w;
    __syncthreads();
    int dr = t >> 3, s4 = (t & 7) * 4;
    ushort4 o;
    o.x = f2bf(tile[s4][dr]);   o.y = f2bf(tile[s4+1][dr]);
    o.z = f2bf(tile[s4+2][dr]); o.w = f2bf(tile[s4+3][dr]);
    *(ushort4*)(Vt + (((size_t)(b * KV_ + kvh)) * HD_ + d0 + dr) * S_ + s0 + s4) = o;
}

// ------------------------------------------------------------------
// flash attention v3: block = (32-row q-tile, kv-head, batch), 8 waves =
// 4 q-heads x 2 q-subtiles sharing one K/V LDS staging (GQA amortization).
__global__ __launch_bounds__(512) void flash_attn(const u16* __restrict__ Qc,
                                                  const u16* __restrict__ Kc,
                                                  const u16* __restrict__ Vt,
                                                  const int* __restrict__ am,
                                                  u16* __restrict__ o) {
    __shared__ __align__(16) u16 Ks[64 * 128];     // [k-row][d], swizzled 16B chunks
    __shared__ __align__(16) u16 Vs[128 * 64];     // [d-row][k], swizzled
    __shared__ __align__(16) u16 Ps[8][16][72];    // per-wave P, padded rows
    __shared__ int am_s[KBLK];
    int qt = blockIdx.x, kvh = blockIdx.y, b = blockIdx.z;
    int tid = threadIdx.x, lane = tid & 63, w = tid >> 6;
    int g = lane >> 4, li = lane & 15;
    int h = kvh * 4 + (w & 3);
    int qrow0 = qt * QT2 + (w >> 2) * 16;          // wave's 16-row q-frag base

    bf16x8 qf[4];
    const u16* qb = Qc + (((size_t)(b * H_ + h)) * S_ + qrow0 + li) * HD_;
    #pragma unroll
    for (int dd = 0; dd < 4; dd++) qf[dd] = *(const bf16x8*)(qb + dd * 32 + g * 8);

    float m_r[4], l_r[4];
    f32x4 oacc[8];
    #pragma unroll
    for (int r = 0; r < 4; r++) { m_r[r] = -1e30f; l_r[r] = 0.f; }
    #pragma unroll
    for (int d = 0; d < 8; d++) oacc[d] = (f32x4){0.f, 0.f, 0.f, 0.f};

    const u16* Kg = Kc + ((size_t)(b * KV_ + kvh)) * S_ * HD_;
    const u16* Vg = Vt + ((size_t)(b * KV_ + kvh)) * HD_ * S_;
    int qg0 = qrow0 + g * 4;
    int nkv = (qt * QT2 + QT2 - 1) >> 6;           // last kv-tile index

    for (int kvt = 0; kvt <= nkv; kvt++) {
        int kv0 = kvt * KBLK;
        // ---- stage K tile (64x128 u16 = 1024 chunks), V^T tile (128x64) ----
        #pragma unroll
        for (int qq = 0; qq < 2; qq++) {
            int u = qq * 512 + tid;
            int krow = u >> 4, p = u & 15;
            gload16(Kg + (size_t)(kv0 + krow) * HD_ + (p ^ (krow & 7)) * 8, (char*)Ks + u * 16);
            int vrow = u >> 3, pv = u & 7;
            gload16(Vg + (size_t)vrow * S_ + kv0 + (pv ^ (vrow & 7)) * 8, (char*)Vs + u * 16);
        }
        if (tid < KBLK) am_s[tid] = am[b * S_ + kv0 + tid];
        __syncthreads();

        if (kv0 <= qrow0 + 15) {    // wave has at least one unmasked row
            // ---- QK^T: S[16q][64k] per wave ----
            float ps[4][4];
            #pragma unroll
            for (int kt = 0; kt < 4; kt++) {
                f32x4 sa = (f32x4){0.f, 0.f, 0.f, 0.f};
                int row = kt * 16 + li;
                #pragma unroll
                for (int dd = 0; dd < 4; dd++) {
                    int c = dd * 4 + g;
                    bf16x8 kf = *(const bf16x8*)((const char*)Ks + ((row * 16 + (c ^ (row & 7))) << 4));
                    sa = __builtin_amdgcn_mfma_f32_16x16x32_bf16(qf[dd], kf, sa, 0, 0, 0);
                }
                int kcol = kv0 + kt * 16 + li;
                int amok = am_s[kt * 16 + li];
                #pragma unroll
                for (int r = 0; r < 4; r++) {
                    float s = sa[r] * 0.08838834764831845f;
                    ps[kt][r] = (amok && kcol <= qg0 + r) ? s : -1e9f;
                }
            }

            // ---- online softmax (row stats across 16-lane col groups) ----
            float rmax[4], rsum[4], scl[4];
            #pragma unroll
            for (int r = 0; r < 4; r++)
                rmax[r] = fmaxf(fmaxf(ps[0][r], ps[1][r]), fmaxf(ps[2][r], ps[3][r]));
            #pragma unroll
            for (int msk = 1; msk < 16; msk <<= 1)
                #pragma unroll
                for (int r = 0; r < 4; r++) rmax[r] = fmaxf(rmax[r], __shfl_xor(rmax[r], msk));
            #pragma unroll
            for (int r = 0; r < 4; r++) {
                float mn = fmaxf(m_r[r], rmax[r]);
                scl[r] = __expf(m_r[r] - mn);
                m_r[r] = mn;
                rsum[r] = 0.f;
            }
            #pragma unroll
            for (int kt = 0; kt < 4; kt++)
                #pragma unroll
                for (int r = 0; r < 4; r++) {
                    float p = __expf(ps[kt][r] - m_r[r]);
                    ps[kt][r] = p;
                    rsum[r] += p;
                }
            #pragma unroll
            for (int msk = 1; msk < 16; msk <<= 1)
                #pragma unroll
                for (int r = 0; r < 4; r++) rsum[r] += __shfl_xor(rsum[r], msk);
            #pragma unroll
            for (int r = 0; r < 4; r++) l_r[r] = l_r[r] * scl[r] + rsum[r];
            #pragma unroll
            for (int d = 0; d < 8; d++)
                #pragma unroll
                for (int r = 0; r < 4; r++) oacc[d][r] *= scl[r];

            // ---- P -> bf16 via per-wave LDS bounce ----
            #pragma unroll
            for (int kt = 0; kt < 4; kt++)
                #pragma unroll
                for (int r = 0; r < 4; r++)
                    Ps[w][g * 4 + r][kt * 16 + li] = f2bf(ps[kt][r]);
            bf16x8 pf[2];
            #pragma unroll
            for (int ks = 0; ks < 2; ks++)
                pf[ks] = *(const bf16x8*)&Ps[w][li][ks * 32 + g * 8];

            // ---- PV: O[16q][128d] += P @ V ----
            #pragma unroll
            for (int dblk = 0; dblk < 8; dblk++) {
                int row = dblk * 16 + li;
                #pragma unroll
                for (int ks = 0; ks < 2; ks++) {
                    int c = ks * 4 + g;
                    bf16x8 vf = *(const bf16x8*)((const char*)Vs + ((row * 8 + (c ^ (row & 7))) << 4));
                    oacc[dblk] = __builtin_amdgcn_mfma_f32_16x16x32_bf16(pf[ks], vf, oacc[dblk], 0, 0, 0);
                }
            }
        }
        __syncthreads();
    }

    // ---- epilogue: O /= l, write bf16 [BS][H][128] ----
    float invl[4];
    #pragma unroll
    for (int r = 0; r < 4; r++) invl[r] = 1.f / l_r[r];
    #pragma unroll
    for (int dblk = 0; dblk < 8; dblk++)
        #pragma unroll
        for (int r = 0; r < 4; r++) {
            int qrow = qg0 + r;
            o[(((size_t)b * S_ + qrow) * H_ + h) * HD_ + dblk * 16 + li] =
                f2bf(oacc[dblk][r] * invl[r]);
        }
}

// ------------------------------------------------------------------
__global__ __launch_bounds__(256) void pool_kernel(const float* __restrict__ h,
                                                   const int* __restrict__ am,
                                                   float* __restrict__ out) {
    int b = blockIdx.y;
    int d = blockIdx.x * 256 + threadIdx.x;
    float acc = 0.f, ms = 0.f;
    for (int s = 0; s < S_; s++) {
        float mm = (float)am[b * S_ + s];
        ms  += mm;
        acc += mm * h[((size_t)b * S_ + s) * D_ + d];
    }
    out[(size_t)b * D_ + d] = acc / fmaxf(ms, 1e-9f);
}

// ------------------------------------------------------------------
extern "C" void kernel_launch(void* const* d_in, const int* in_sizes, int n_in,
                              void* d_out, int out_size, void* d_ws, size_t ws_size,
                              hipStream_t stream) {
    const float* embed = (const float*)d_in[0];
    const float* wq    = (const float*)d_in[1];
    const float* wk    = (const float*)d_in[2];
    const float* wv    = (const float*)d_in[3];
    const float* wo    = (const float*)d_in[4];
    const float* laq   = (const float*)d_in[5];
    const float* lbq   = (const float*)d_in[6];
    const float* lav   = (const float*)d_in[7];
    const float* lbv   = (const float*)d_in[8];
    const float* wg    = (const float*)d_in[9];
    const float* wu    = (const float*)d_in[10];
    const float* wd    = (const float*)d_in[11];
    const float* n1    = (const float*)d_in[12];
    const float* n2    = (const float*)d_in[13];
    const float* nf    = (const float*)d_in[14];
    const int*   ids   = (const int*)d_in[15];
    const int*   am    = (const int*)d_in[16];
    float* out = (float*)d_out;

    char* base = (char*)d_ws;
    float* x   = (float*)base;                          // 33.55 MB f32
    u16*   hbf = (u16*)(base + 33554432);               // 16.78 MB bf16
    u16*   obf = (u16*)(base + 50331648);               // 16.78 MB bf16
    char*  Rg  = base + 67108864;                       // 67.11 MB multi-purpose
    float* q   = (float*)Rg;                            // 33.55 MB f32
    float* kb  = (float*)(Rg + 33554432);               // 8.39 MB f32
    float* vb  = (float*)(Rg + 41943040);               // 8.39 MB f32
    u16*   act = (u16*)Rg;                              // 67.11 MB bf16 (after attn)
    float* hf  = (float*)Rg;                            // final norm f32 (after MLP)
    float* t16 = (float*)(base + 134217728);            // 0.26 MB
    u16*   wT0 = (u16*)(base + 134479872);              // 33.55 MB bf16
    u16*   wT1 = (u16*)(base + 168034304);              // 33.55 MB bf16
    u16*   Qc  = (u16*)(base + 201588736);              // 16.78 MB bf16
    u16*   Kc  = (u16*)(base + 218365952);              // 4.19 MB bf16
    u16*   Vtb = (u16*)(base + 222560256);              // 4.19 MB bf16
    // total ~226.8 MB

    embed_kernel<<<BS_, 256, 0, stream>>>(embed, ids, x);

    for (int l = 0; l < NL_; l++) {
        const float* wql = wq + (size_t)l * D_ * D_;
        const float* wkl = wk + (size_t)l * D_ * (KV_*HD_);
        const float* wvl = wv + (size_t)l * D_ * (KV_*HD_);
        const float* wol = wo + (size_t)l * D_ * D_;
        const float* wgl = wg + (size_t)l * D_ * F_;
        const float* wul = wu + (size_t)l * D_ * F_;
        const float* wdl = wd + (size_t)l * F_ * D_;

        rmsnorm_kernel<1><<<BS_, 256, 0, stream>>>(x, n1 + (size_t)l * D_, hbf);

        // q projection
        convt_kernel<<<dim3(D_/32, D_/32), 256, 0, stream>>>(wql, wT0, D_, D_);
        gemm_bt<0><<<dim3(D_/128, BS_/128), 256, 0, stream>>>(hbf, wT0, q, D_, D_);
        lora_a_kernel<<<BS_/16, 256, 0, stream>>>(hbf, laq + (size_t)l * R_ * D_, t16);
        lora_b_kernel<<<BS_, 256, 0, stream>>>(t16, lbq + (size_t)l * D_ * R_, q, D_);

        // k, v projections
        convt_kernel<<<dim3((KV_*HD_)/32, D_/32), 256, 0, stream>>>(wkl, wT0, D_, KV_*HD_);
        gemm_bt<0><<<dim3((KV_*HD_)/128, BS_/128), 256, 0, stream>>>(hbf, wT0, kb, KV_*HD_, D_);
        convt_kernel<<<dim3((KV_*HD_)/32, D_/32), 256, 0, stream>>>(wvl, wT0, D_, KV_*HD_);
        gemm_bt<0><<<dim3((KV_*HD_)/128, BS_/128), 256, 0, stream>>>(hbf, wT0, vb, KV_*HD_, D_);
        lora_a_kernel<<<BS_/16, 256, 0, stream>>>(hbf, lav + (size_t)l * R_ * D_, t16);
        lora_b_kernel<<<BS_, 256, 0, stream>>>(t16, lbv + (size_t)l * (KV_*HD_) * R_, vb, KV_*HD_);

        // RoPE + layout conversion for attention
        qconv_rope<<<dim3(BS_, H_),  64, 0, stream>>>(q,  Qc);
        kconv_rope<<<dim3(BS_, KV_), 64, 0, stream>>>(kb, Kc);
        vconv_t<<<dim3(S_/32, HD_/32, B_*KV_), 256, 0, stream>>>(vb, Vtb);

        flash_attn<<<dim3(S_/QT2, KV_, B_), 512, 0, stream>>>(Qc, Kc, Vtb, am, obf);

        // o projection (accumulate into residual x)
        convt_kernel<<<dim3(D_/32, D_/32), 256, 0, stream>>>(wol, wT0, D_, D_);
        gemm_bt<1><<<dim3(D_/128, BS_/128), 256, 0, stream>>>(obf, wT0, x, D_, D_);

        // MLP
        rmsnorm_kernel<1><<<BS_, 256, 0, stream>>>(x, n2 + (size_t)l * D_, hbf);
        convt_kernel<<<dim3(F_/32, D_/32), 256, 0, stream>>>(wgl, wT0, D_, F_);
        convt_kernel<<<dim3(F_/32, D_/32), 256, 0, stream>>>(wul, wT1, D_, F_);
        gemm_gateup_bt<<<dim3(F_/128, BS_/128), 256, 0, stream>>>(hbf, wT0, wT1, act, F_, D_);
        convt_kernel<<<dim3(D_/32, F_/32), 256, 0, stream>>>(wdl, wT0, F_, D_);
        gemm_bt<1><<<dim3(D_/128, BS_/128), 256, 0, stream>>>(act, wT0, x, D_, F_);
    }

    rmsnorm_kernel<0><<<BS_, 256, 0, stream>>>(x, nf, hf);
    pool_kernel<<<dim3(D_/256, B_), 256, 0, stream>>>(hf, am, out);
}

// Round 7
// 2175.817 us; speedup vs baseline: 1.1292x; 1.1292x over previous
//
#include <hip/hip_runtime.h>
#include <math.h>

#define B_  4
#define S_  1024
#define D_  2048
#define NL_ 2
#define H_  16
#define KV_ 4
#define F_  8192
#define R_  16
#define HD_ 128
#define BS_ (B_*S_)   // 4096 tokens
#define QT2 32
#define KBLK 64

typedef unsigned short u16;
typedef __attribute__((ext_vector_type(8))) __bf16 bf16x8;
typedef __attribute__((ext_vector_type(4))) float  f32x4;

__device__ __forceinline__ u16 f2bf(float f) {
    unsigned x = __float_as_uint(f);
    unsigned r = (x + 0x7fffu + ((x >> 16) & 1u)) >> 16;   // RNE
    return (u16)r;
}
__device__ __forceinline__ float bf2f(u16 u) {
    return __uint_as_float(((unsigned)u) << 16);
}

// async global->LDS, 16B per lane. LDS dest must be linear (base + lane*16).
__device__ __forceinline__ void gload16(const void* g, void* l) {
    __builtin_amdgcn_global_load_lds((const __attribute__((address_space(1))) void*)g,
                                     (__attribute__((address_space(3))) void*)l, 16, 0, 0);
}

// ------------------------------------------------------------------
__global__ void embed_kernel(const float* __restrict__ embed,
                             const int* __restrict__ ids,
                             float* __restrict__ x) {
    int tok = blockIdx.x;
    int id  = ids[tok];
    const float4* src = (const float4*)(embed + (size_t)id * D_);
    float4*       dst = (float4*)(x + (size_t)tok * D_);
    for (int i = threadIdx.x; i < D_/4; i += blockDim.x) dst[i] = src[i];
}

// ------------------------------------------------------------------
template<int OUTBF>
__global__ __launch_bounds__(256) void rmsnorm_kernel(const float* __restrict__ x,
                                                      const float* __restrict__ w,
                                                      void* __restrict__ out) {
    int row = blockIdx.x;
    const float4* xr = (const float4*)(x + (size_t)row * D_);
    float ss = 0.f;
    for (int i = threadIdx.x; i < D_/4; i += 256) {
        float4 v = xr[i];
        ss += v.x*v.x + v.y*v.y + v.z*v.z + v.w*v.w;
    }
    __shared__ float red[4];
    for (int off = 32; off; off >>= 1) ss += __shfl_down(ss, off);
    if ((threadIdx.x & 63) == 0) red[threadIdx.x >> 6] = ss;
    __syncthreads();
    float tot = red[0] + red[1] + red[2] + red[3];
    float scale = rsqrtf(tot / (float)D_ + 1e-5f);
    const float4* w4 = (const float4*)w;
    for (int i = threadIdx.x; i < D_/4; i += 256) {
        float4 v = xr[i], g = w4[i];
        float a = v.x*scale*g.x, b = v.y*scale*g.y, c = v.z*scale*g.z, d = v.w*scale*g.w;
        if (OUTBF) {
            ushort4 o; o.x = f2bf(a); o.y = f2bf(b); o.z = f2bf(c); o.w = f2bf(d);
            ((ushort4*)((u16*)out + (size_t)row * D_))[i] = o;
        } else {
            float4 o; o.x = a; o.y = b; o.z = c; o.w = d;
            ((float4*)((float*)out + (size_t)row * D_))[i] = o;
        }
    }
}

// ------------------------------------------------------------------
// transpose + f32->bf16: in [K][N] f32 row-major  ->  out [N][K] bf16 row-major
__global__ __launch_bounds__(256) void convt_kernel(const float* __restrict__ in,
                                                    u16* __restrict__ outT,
                                                    int K, int N) {
    __shared__ float tile[32][33];
    int k0 = blockIdx.y * 32, n0 = blockIdx.x * 32;
    int t = threadIdx.x;
    int r = t >> 3, c4 = (t & 7) * 4;
    float4 v = *(const float4*)(in + (size_t)(k0 + r) * N + n0 + c4);
    tile[r][c4] = v.x; tile[r][c4+1] = v.y; tile[r][c4+2] = v.z; tile[r][c4+3] = v.w;
    __syncthreads();
    int n = t >> 3, kc = (t & 7) * 4;
    ushort4 o;
    o.x = f2bf(tile[kc][n]);   o.y = f2bf(tile[kc+1][n]);
    o.z = f2bf(tile[kc+2][n]); o.w = f2bf(tile[kc+3][n]);
    *(ushort4*)(outT + (size_t)(n0 + n) * K + k0 + kc) = o;
}

// ------------------------------------------------------------------
// MFMA GEMM, B transposed: C[M,N] (+)= A[M,K](bf16) @ Bt[N,K](bf16)^T, C f32
template<int ACC>
__global__ __launch_bounds__(256) void gemm_bt(const u16* __restrict__ A,
                                               const u16* __restrict__ Bt,
                                               float* __restrict__ C,
                                               int N, int K) {
    __shared__ __align__(16) u16 As[128*64];
    __shared__ __align__(16) u16 Bs[128*64];
    int tid = threadIdx.x, lane = tid & 63;
    int wid = tid >> 6, wm = wid >> 1, wn = wid & 1;
    int m0 = blockIdx.y * 128, n0 = blockIdx.x * 128;
    const u16* Ab = A  + (size_t)m0 * K;
    const u16* Bb = Bt + (size_t)n0 * K;
    f32x4 acc[4][4] = {};
    for (int k0 = 0; k0 < K; k0 += 64) {
        #pragma unroll
        for (int qq = 0; qq < 4; qq++) {
            int u = qq * 256 + tid;
            int row = u >> 3, cu = u & 7, scu = cu ^ (row & 7);
            size_t goff = (size_t)row * K + k0 + scu * 8;
            gload16(Ab + goff, (char*)As + u * 16);
            gload16(Bb + goff, (char*)Bs + u * 16);
        }
        __syncthreads();
        #pragma unroll
        for (int kk = 0; kk < 2; kk++) {
            int cu = kk * 4 + (lane >> 4);
            bf16x8 af[4], bfr[4];
            #pragma unroll
            for (int i = 0; i < 4; i++) {
                int ar = wm * 64 + i * 16 + (lane & 15);
                af[i]  = *(const bf16x8*)((const char*)As + (((ar << 3) | (cu ^ (ar & 7))) << 4));
                int br = wn * 64 + i * 16 + (lane & 15);
                bfr[i] = *(const bf16x8*)((const char*)Bs + (((br << 3) | (cu ^ (br & 7))) << 4));
            }
            #pragma unroll
            for (int i = 0; i < 4; i++)
                #pragma unroll
                for (int j = 0; j < 4; j++)
                    acc[i][j] = __builtin_amdgcn_mfma_f32_16x16x32_bf16(af[i], bfr[j], acc[i][j], 0, 0, 0);
        }
        __syncthreads();
    }
    int r0 = (lane >> 4) * 4, c0 = lane & 15;
    #pragma unroll
    for (int i = 0; i < 4; i++)
        #pragma unroll
        for (int j = 0; j < 4; j++) {
            int row = m0 + wm * 64 + i * 16 + r0;
            int col = n0 + wn * 64 + j * 16 + c0;
            float* cp = C + (size_t)row * N + col;
            #pragma unroll
            for (int r = 0; r < 4; r++) {
                if (ACC) cp[(size_t)r * N] += acc[i][j][r];
                else     cp[(size_t)r * N] = acc[i][j][r];
            }
        }
}

// ------------------------------------------------------------------
// fused gate/up MFMA GEMM: act = silu(A@G) * (A@U), 128x64 tile, 4 waves.
__global__ __launch_bounds__(256) void gemm_gateup_bt(const u16* __restrict__ A,
                                                      const u16* __restrict__ Gt,
                                                      const u16* __restrict__ Ut,
                                                      u16* __restrict__ act,
                                                      int N, int K) {
    __shared__ __align__(16) u16 As[128*64];
    __shared__ __align__(16) u16 Gs[64*64];
    __shared__ __align__(16) u16 Us[64*64];
    int tid = threadIdx.x, lane = tid & 63;
    int wid = tid >> 6, wm = wid >> 1, wn = wid & 1;
    int m0 = blockIdx.y * 128, n0 = blockIdx.x * 64;
    const u16* Ab = A  + (size_t)m0 * K;
    const u16* Gb = Gt + (size_t)n0 * K;
    const u16* Ub = Ut + (size_t)n0 * K;
    f32x4 ag[4][2] = {}, au[4][2] = {};
    for (int k0 = 0; k0 < K; k0 += 64) {
        #pragma unroll
        for (int qq = 0; qq < 4; qq++) {
            int u = qq * 256 + tid;
            int row = u >> 3, cu = u & 7, scu = cu ^ (row & 7);
            gload16(Ab + (size_t)row * K + k0 + scu * 8, (char*)As + u * 16);
        }
        #pragma unroll
        for (int qq = 0; qq < 2; qq++) {
            int u = qq * 256 + tid;
            int row = u >> 3, cu = u & 7, scu = cu ^ (row & 7);
            size_t goff = (size_t)row * K + k0 + scu * 8;
            gload16(Gb + goff, (char*)Gs + u * 16);
            gload16(Ub + goff, (char*)Us + u * 16);
        }
        __syncthreads();
        #pragma unroll
        for (int kk = 0; kk < 2; kk++) {
            int cu = kk * 4 + (lane >> 4);
            bf16x8 af[4], gf[2], uf[2];
            #pragma unroll
            for (int i = 0; i < 4; i++) {
                int ar = wm * 64 + i * 16 + (lane & 15);
                af[i] = *(const bf16x8*)((const char*)As + (((ar << 3) | (cu ^ (ar & 7))) << 4));
            }
            #pragma unroll
            for (int j = 0; j < 2; j++) {
                int br = wn * 32 + j * 16 + (lane & 15);
                int off = ((br << 3) | (cu ^ (br & 7))) << 4;
                gf[j] = *(const bf16x8*)((const char*)Gs + off);
                uf[j] = *(const bf16x8*)((const char*)Us + off);
            }
            #pragma unroll
            for (int i = 0; i < 4; i++)
                #pragma unroll
                for (int j = 0; j < 2; j++) {
                    ag[i][j] = __builtin_amdgcn_mfma_f32_16x16x32_bf16(af[i], gf[j], ag[i][j], 0, 0, 0);
                    au[i][j] = __builtin_amdgcn_mfma_f32_16x16x32_bf16(af[i], uf[j], au[i][j], 0, 0, 0);
                }
        }
        __syncthreads();
    }
    int r0 = (lane >> 4) * 4, c0 = lane & 15;
    #pragma unroll
    for (int i = 0; i < 4; i++)
        #pragma unroll
        for (int j = 0; j < 2; j++) {
            int col = n0 + wn * 32 + j * 16 + c0;
            #pragma unroll
            for (int r = 0; r < 4; r++) {
                int row = m0 + wm * 64 + i * 16 + r0 + r;
                float g = ag[i][j][r], u = au[i][j][r];
                float s = g / (1.f + __expf(-g));
                act[(size_t)row * N + col] = f2bf(s * u);
            }
        }
}

// ------------------------------------------------------------------
// LoRA
__global__ __launch_bounds__(256) void lora_a_kernel(const u16* __restrict__ h,
                                                     const float* __restrict__ la,
                                                     float* __restrict__ t16) {
    int r = threadIdx.x >> 4;
    int c = threadIdx.x & 15;
    int row = blockIdx.x * 16 + r;
    const ushort4* hr = (const ushort4*)(h + (size_t)row * D_);
    const float4* lr = (const float4*)(la + (size_t)c * D_);
    float acc = 0.f;
    #pragma unroll 4
    for (int i = 0; i < D_/4; i++) {
        ushort4 a = hr[i]; float4 b = lr[i];
        acc += bf2f(a.x)*b.x + bf2f(a.y)*b.y + bf2f(a.z)*b.z + bf2f(a.w)*b.w;
    }
    t16[(size_t)row * R_ + c] = acc;
}

__global__ __launch_bounds__(256) void lora_b_kernel(const float* __restrict__ t16,
                                                     const float* __restrict__ lb,
                                                     float* __restrict__ out, int N) {
    int row = blockIdx.x;
    __shared__ float ts[R_];
    if (threadIdx.x < R_) ts[threadIdx.x] = t16[(size_t)row * R_ + threadIdx.x];
    __syncthreads();
    for (int d = threadIdx.x; d < N; d += 256) {
        const float4* lbr = (const float4*)(lb + (size_t)d * R_);
        float acc = 0.f;
        #pragma unroll
        for (int r4 = 0; r4 < 4; r4++) {
            float4 v = lbr[r4];
            acc += v.x*ts[r4*4] + v.y*ts[r4*4+1] + v.z*ts[r4*4+2] + v.w*ts[r4*4+3];
        }
        out[(size_t)row * N + d] += 2.0f * acc;
    }
}

// ------------------------------------------------------------------
// fused RoPE + f32->bf16 conv, Q: [BS,H,128] f32 -> Qc [B][H][S][128] bf16
__global__ void qconv_rope(const float* __restrict__ q, u16* __restrict__ Qc) {
    int tok = blockIdx.x, h = blockIdx.y, t = threadIdx.x;   // t: 0..63
    int b = tok >> 10, s = tok & (S_ - 1);
    float inv = __expf(-(float)t * (13.122363377404328f / 64.0f));
    float f = (float)s * inv;
    float c = __cosf(f), si = __sinf(f);
    const float* src = q + ((size_t)tok * H_ + h) * HD_;
    float x0 = src[t], x1 = src[t + 64];
    u16* dst = Qc + (((size_t)(b * H_ + h)) * S_ + s) * HD_;
    dst[t]      = f2bf(x0 * c - x1 * si);
    dst[t + 64] = f2bf(x1 * c + x0 * si);
}

// K: [BS,KV,128] f32 -> Kc [B][KV][S][128] bf16 (with RoPE)
__global__ void kconv_rope(const float* __restrict__ k, u16* __restrict__ Kc) {
    int tok = blockIdx.x, h = blockIdx.y, t = threadIdx.x;
    int b = tok >> 10, s = tok & (S_ - 1);
    float inv = __expf(-(float)t * (13.122363377404328f / 64.0f));
    float f = (float)s * inv;
    float c = __cosf(f), si = __sinf(f);
    const float* src = k + ((size_t)tok * KV_ + h) * HD_;
    float x0 = src[t], x1 = src[t + 64];
    u16* dst = Kc + (((size_t)(b * KV_ + h)) * S_ + s) * HD_;
    dst[t]      = f2bf(x0 * c - x1 * si);
    dst[t + 64] = f2bf(x1 * c + x0 * si);
}

// V: [BS,KV,128] f32 -> Vt [B][KV][128][S] bf16 (transposed)
__global__ __launch_bounds__(256) void vconv_t(const float* __restrict__ vb,
                                               u16* __restrict__ Vt) {
    __shared__ float tile[32][33];
    int s0 = blockIdx.x * 32, d0 = blockIdx.y * 32;
    int bk = blockIdx.z;
    int b = bk >> 2, kvh = bk & 3;
    int t = threadIdx.x;
    int r = t >> 3, c4 = (t & 7) * 4;
    float4 v = *(const float4*)(vb + (((size_t)(b * S_ + s0 + r)) * KV_ + kvh) * HD_ + d0 + c4);
    tile[r][c4] = v.x; tile[r][c4+1] = v.y; tile[r][c4+2] = v.z; tile[r][c4+3] = v.w;
    __syncthreads();
    int dr = t >> 3, s4 = (t & 7) * 4;
    ushort4 o;
    o.x = f2bf(tile[s4][dr]);   o.y = f2bf(tile[s4+1][dr]);
    o.z = f2bf(tile[s4+2][dr]); o.w = f2bf(tile[s4+3][dr]);
    *(ushort4*)(Vt + (((size_t)(b * KV_ + kvh)) * HD_ + d0 + dr) * S_ + s0 + s4) = o;
}

// ------------------------------------------------------------------
// flash attention v3: block = (32-row q-tile, kv-head, batch), 8 waves =
// 4 q-heads x 2 q-subtiles sharing one K/V LDS staging (GQA amortization).
__global__ __launch_bounds__(512) void flash_attn(const u16* __restrict__ Qc,
                                                  const u16* __restrict__ Kc,
                                                  const u16* __restrict__ Vt,
                                                  const int* __restrict__ am,
                                                  u16* __restrict__ o) {
    __shared__ __align__(16) u16 Ks[64 * 128];     // [k-row][d], swizzled 16B chunks
    __shared__ __align__(16) u16 Vs[128 * 64];     // [d-row][k], swizzled
    __shared__ __align__(16) u16 Ps[8][16][72];    // per-wave P, padded rows
    __shared__ int am_s[KBLK];
    int qt = blockIdx.x, kvh = blockIdx.y, b = blockIdx.z;
    int tid = threadIdx.x, lane = tid & 63, w = tid >> 6;
    int g = lane >> 4, li = lane & 15;
    int h = kvh * 4 + (w & 3);
    int qrow0 = qt * QT2 + (w >> 2) * 16;          // wave's 16-row q-frag base

    bf16x8 qf[4];
    const u16* qb = Qc + (((size_t)(b * H_ + h)) * S_ + qrow0 + li) * HD_;
    #pragma unroll
    for (int dd = 0; dd < 4; dd++) qf[dd] = *(const bf16x8*)(qb + dd * 32 + g * 8);

    float m_r[4], l_r[4];
    f32x4 oacc[8];
    #pragma unroll
    for (int r = 0; r < 4; r++) { m_r[r] = -1e30f; l_r[r] = 0.f; }
    #pragma unroll
    for (int d = 0; d < 8; d++) oacc[d] = (f32x4){0.f, 0.f, 0.f, 0.f};

    const u16* Kg = Kc + ((size_t)(b * KV_ + kvh)) * S_ * HD_;
    const u16* Vg = Vt + ((size_t)(b * KV_ + kvh)) * HD_ * S_;
    int qg0 = qrow0 + g * 4;
    int nkv = (qt * QT2 + QT2 - 1) >> 6;           // last kv-tile index

    for (int kvt = 0; kvt <= nkv; kvt++) {
        int kv0 = kvt * KBLK;
        // ---- stage K tile (64x128 u16 = 1024 chunks), V^T tile (128x64) ----
        #pragma unroll
        for (int qq = 0; qq < 2; qq++) {
            int u = qq * 512 + tid;
            int krow = u >> 4, p = u & 15;
            gload16(Kg + (size_t)(kv0 + krow) * HD_ + (p ^ (krow & 7)) * 8, (char*)Ks + u * 16);
            int vrow = u >> 3, pv = u & 7;
            gload16(Vg + (size_t)vrow * S_ + kv0 + (pv ^ (vrow & 7)) * 8, (char*)Vs + u * 16);
        }
        if (tid < KBLK) am_s[tid] = am[b * S_ + kv0 + tid];
        __syncthreads();

        if (kv0 <= qrow0 + 15) {    // wave has at least one unmasked row
            // ---- QK^T: S[16q][64k] per wave ----
            float ps[4][4];
            #pragma unroll
            for (int kt = 0; kt < 4; kt++) {
                f32x4 sa = (f32x4){0.f, 0.f, 0.f, 0.f};
                int row = kt * 16 + li;
                #pragma unroll
                for (int dd = 0; dd < 4; dd++) {
                    int c = dd * 4 + g;
                    bf16x8 kf = *(const bf16x8*)((const char*)Ks + ((row * 16 + (c ^ (row & 7))) << 4));
                    sa = __builtin_amdgcn_mfma_f32_16x16x32_bf16(qf[dd], kf, sa, 0, 0, 0);
                }
                int kcol = kv0 + kt * 16 + li;
                int amok = am_s[kt * 16 + li];
                #pragma unroll
                for (int r = 0; r < 4; r++) {
                    float s = sa[r] * 0.08838834764831845f;
                    ps[kt][r] = (amok && kcol <= qg0 + r) ? s : -1e9f;
                }
            }

            // ---- online softmax (row stats across 16-lane col groups) ----
            float rmax[4], rsum[4], scl[4];
            #pragma unroll
            for (int r = 0; r < 4; r++)
                rmax[r] = fmaxf(fmaxf(ps[0][r], ps[1][r]), fmaxf(ps[2][r], ps[3][r]));
            #pragma unroll
            for (int msk = 1; msk < 16; msk <<= 1)
                #pragma unroll
                for (int r = 0; r < 4; r++) rmax[r] = fmaxf(rmax[r], __shfl_xor(rmax[r], msk));
            #pragma unroll
            for (int r = 0; r < 4; r++) {
                float mn = fmaxf(m_r[r], rmax[r]);
                scl[r] = __expf(m_r[r] - mn);
                m_r[r] = mn;
                rsum[r] = 0.f;
            }
            #pragma unroll
            for (int kt = 0; kt < 4; kt++)
                #pragma unroll
                for (int r = 0; r < 4; r++) {
                    float p = __expf(ps[kt][r] - m_r[r]);
                    ps[kt][r] = p;
                    rsum[r] += p;
                }
            #pragma unroll
            for (int msk = 1; msk < 16; msk <<= 1)
                #pragma unroll
                for (int r = 0; r < 4; r++) rsum[r] += __shfl_xor(rsum[r], msk);
            #pragma unroll
            for (int r = 0; r < 4; r++) l_r[r] = l_r[r] * scl[r] + rsum[r];
            #pragma unroll
            for (int d = 0; d < 8; d++)
                #pragma unroll
                for (int r = 0; r < 4; r++) oacc[d][r] *= scl[r];

            // ---- P -> bf16 via per-wave LDS bounce ----
            #pragma unroll
            for (int kt = 0; kt < 4; kt++)
                #pragma unroll
                for (int r = 0; r < 4; r++)
                    Ps[w][g * 4 + r][kt * 16 + li] = f2bf(ps[kt][r]);
            bf16x8 pf[2];
            #pragma unroll
            for (int ks = 0; ks < 2; ks++)
                pf[ks] = *(const bf16x8*)&Ps[w][li][ks * 32 + g * 8];

            // ---- PV: O[16q][128d] += P @ V ----
            #pragma unroll
            for (int dblk = 0; dblk < 8; dblk++) {
                int row = dblk * 16 + li;
                #pragma unroll
                for (int ks = 0; ks < 2; ks++) {
                    int c = ks * 4 + g;
                    bf16x8 vf = *(const bf16x8*)((const char*)Vs + ((row * 8 + (c ^ (row & 7))) << 4));
                    oacc[dblk] = __builtin_amdgcn_mfma_f32_16x16x32_bf16(pf[ks], vf, oacc[dblk], 0, 0, 0);
                }
            }
        }
        __syncthreads();
    }

    // ---- epilogue: O /= l, write bf16 [BS][H][128] ----
    float invl[4];
    #pragma unroll
    for (int r = 0; r < 4; r++) invl[r] = 1.f / l_r[r];
    #pragma unroll
    for (int dblk = 0; dblk < 8; dblk++)
        #pragma unroll
        for (int r = 0; r < 4; r++) {
            int qrow = qg0 + r;
            o[(((size_t)b * S_ + qrow) * H_ + h) * HD_ + dblk * 16 + li] =
                f2bf(oacc[dblk][r] * invl[r]);
        }
}

// ------------------------------------------------------------------
__global__ __launch_bounds__(256) void pool_kernel(const float* __restrict__ h,
                                                   const int* __restrict__ am,
                                                   float* __restrict__ out) {
    int b = blockIdx.y;
    int d = blockIdx.x * 256 + threadIdx.x;
    float acc = 0.f, ms = 0.f;
    for (int s = 0; s < S_; s++) {
        float mm = (float)am[b * S_ + s];
        ms  += mm;
        acc += mm * h[((size_t)b * S_ + s) * D_ + d];
    }
    out[(size_t)b * D_ + d] = acc / fmaxf(ms, 1e-9f);
}

// ------------------------------------------------------------------
extern "C" void kernel_launch(void* const* d_in, const int* in_sizes, int n_in,
                              void* d_out, int out_size, void* d_ws, size_t ws_size,
                              hipStream_t stream) {
    const float* embed = (const float*)d_in[0];
    const float* wq    = (const float*)d_in[1];
    const float* wk    = (const float*)d_in[2];
    const float* wv    = (const float*)d_in[3];
    const float* wo    = (const float*)d_in[4];
    const float* laq   = (const float*)d_in[5];
    const float* lbq   = (const float*)d_in[6];
    const float* lav   = (const float*)d_in[7];
    const float* lbv   = (const float*)d_in[8];
    const float* wg    = (const float*)d_in[9];
    const float* wu    = (const float*)d_in[10];
    const float* wd    = (const float*)d_in[11];
    const float* n1    = (const float*)d_in[12];
    const float* n2    = (const float*)d_in[13];
    const float* nf    = (const float*)d_in[14];
    const int*   ids   = (const int*)d_in[15];
    const int*   am    = (const int*)d_in[16];
    float* out = (float*)d_out;

    char* base = (char*)d_ws;
    float* x   = (float*)base;                          // 33.55 MB f32
    u16*   hbf = (u16*)(base + 33554432);               // 16.78 MB bf16
    u16*   obf = (u16*)(base + 50331648);               // 16.78 MB bf16
    char*  Rg  = base + 67108864;                       // 67.11 MB multi-purpose
    float* q   = (float*)Rg;                            // 33.55 MB f32
    float* kb  = (float*)(Rg + 33554432);               // 8.39 MB f32
    float* vb  = (float*)(Rg + 41943040);               // 8.39 MB f32
    u16*   act = (u16*)Rg;                              // 67.11 MB bf16 (after attn)
    float* hf  = (float*)Rg;                            // final norm f32 (after MLP)
    float* t16 = (float*)(base + 134217728);            // 0.26 MB
    u16*   wT0 = (u16*)(base + 134479872);              // 33.55 MB bf16
    u16*   wT1 = (u16*)(base + 168034304);              // 33.55 MB bf16
    u16*   Qc  = (u16*)(base + 201588736);              // 16.78 MB bf16
    u16*   Kc  = (u16*)(base + 218365952);              // 4.19 MB bf16
    u16*   Vtb = (u16*)(base + 222560256);              // 4.19 MB bf16
    // total ~226.8 MB

    embed_kernel<<<BS_, 256, 0, stream>>>(embed, ids, x);

    for (int l = 0; l < NL_; l++) {
        const float* wql = wq + (size_t)l * D_ * D_;
        const float* wkl = wk + (size_t)l * D_ * (KV_*HD_);
        const float* wvl = wv + (size_t)l * D_ * (KV_*HD_);
        const float* wol = wo + (size_t)l * D_ * D_;
        const float* wgl = wg + (size_t)l * D_ * F_;
        const float* wul = wu + (size_t)l * D_ * F_;
        const float* wdl = wd + (size_t)l * F_ * D_;

        rmsnorm_kernel<1><<<BS_, 256, 0, stream>>>(x, n1 + (size_t)l * D_, hbf);

        // q projection
        convt_kernel<<<dim3(D_/32, D_/32), 256, 0, stream>>>(wql, wT0, D_, D_);
        gemm_bt<0><<<dim3(D_/128, BS_/128), 256, 0, stream>>>(hbf, wT0, q, D_, D_);
        lora_a_kernel<<<BS_/16, 256, 0, stream>>>(hbf, laq + (size_t)l * R_ * D_, t16);
        lora_b_kernel<<<BS_, 256, 0, stream>>>(t16, lbq + (size_t)l * D_ * R_, q, D_);

        // k, v projections
        convt_kernel<<<dim3((KV_*HD_)/32, D_/32), 256, 0, stream>>>(wkl, wT0, D_, KV_*HD_);
        gemm_bt<0><<<dim3((KV_*HD_)/128, BS_/128), 256, 0, stream>>>(hbf, wT0, kb, KV_*HD_, D_);
        convt_kernel<<<dim3((KV_*HD_)/32, D_/32), 256, 0, stream>>>(wvl, wT0, D_, KV_*HD_);
        gemm_bt<0><<<dim3((KV_*HD_)/128, BS_/128), 256, 0, stream>>>(hbf, wT0, vb, KV_*HD_, D_);
        lora_a_kernel<<<BS_/16, 256, 0, stream>>>(hbf, lav + (size_t)l * R_ * D_, t16);
        lora_b_kernel<<<BS_, 256, 0, stream>>>(t16, lbv + (size_t)l * (KV_*HD_) * R_, vb, KV_*HD_);

        // RoPE + layout conversion for attention
        qconv_rope<<<dim3(BS_, H_),  64, 0, stream>>>(q,  Qc);
        kconv_rope<<<dim3(BS_, KV_), 64, 0, stream>>>(kb, Kc);
        vconv_t<<<dim3(S_/32, HD_/32, B_*KV_), 256, 0, stream>>>(vb, Vtb);

        flash_attn<<<dim3(S_/QT2, KV_, B_), 512, 0, stream>>>(Qc, Kc, Vtb, am, obf);

        // o projection (accumulate into residual x)
        convt_kernel<<<dim3(D_/32, D_/32), 256, 0, stream>>>(wol, wT0, D_, D_);
        gemm_bt<1><<<dim3(D_/128, BS_/128), 256, 0, stream>>>(obf, wT0, x, D_, D_);

        // MLP
        rmsnorm_kernel<1><<<BS_, 256, 0, stream>>>(x, n2 + (size_t)l * D_, hbf);
        convt_kernel<<<dim3(F_/32, D_/32), 256, 0, stream>>>(wgl, wT0, D_, F_);
        convt_kernel<<<dim3(F_/32, D_/32), 256, 0, stream>>>(wul, wT1, D_, F_);
        gemm_gateup_bt<<<dim3(F_/64, BS_/128), 256, 0, stream>>>(hbf, wT0, wT1, act, F_, D_);
        convt_kernel<<<dim3(D_/32, F_/32), 256, 0, stream>>>(wdl, wT0, F_, D_);
        gemm_bt<1><<<dim3(D_/128, BS_/128), 256, 0, stream>>>(act, wT0, x, D_, F_);
    }

    rmsnorm_kernel<0><<<BS_, 256, 0, stream>>>(x, nf, hf);
    pool_kernel<<<dim3(D_/256, B_), 256, 0, stream>>>(hf, am, out);
}

// Round 8
// 2117.885 us; speedup vs baseline: 1.1601x; 1.0274x over previous
//
#include <hip/hip_runtime.h>
#include <math.h>

#define B_  4
#define S_  1024
#define D_  2048
#define NL_ 2
#define H_  16
#define KV_ 4
#define F_  8192
#define R_  16
#define HD_ 128
#define BS_ (B_*S_)   // 4096 tokens
#define QT2 32
#define KBLK 64

typedef unsigned short u16;
typedef __attribute__((ext_vector_type(8))) __bf16 bf16x8;
typedef __attribute__((ext_vector_type(4))) float  f32x4;

__device__ __forceinline__ u16 f2bf(float f) {
    unsigned x = __float_as_uint(f);
    unsigned r = (x + 0x7fffu + ((x >> 16) & 1u)) >> 16;   // RNE
    return (u16)r;
}
__device__ __forceinline__ float bf2f(u16 u) {
    return __uint_as_float(((unsigned)u) << 16);
}

// async global->LDS, 16B per lane. LDS dest must be linear (base + lane*16).
__device__ __forceinline__ void gload16(const void* g, void* l) {
    __builtin_amdgcn_global_load_lds((const __attribute__((address_space(1))) void*)g,
                                     (__attribute__((address_space(3))) void*)l, 16, 0, 0);
}

// ------------------------------------------------------------------
__global__ void embed_kernel(const float* __restrict__ embed,
                             const int* __restrict__ ids,
                             float* __restrict__ x) {
    int tok = blockIdx.x;
    int id  = ids[tok];
    const float4* src = (const float4*)(embed + (size_t)id * D_);
    float4*       dst = (float4*)(x + (size_t)tok * D_);
    for (int i = threadIdx.x; i < D_/4; i += blockDim.x) dst[i] = src[i];
}

// ------------------------------------------------------------------
template<int OUTBF>
__global__ __launch_bounds__(256) void rmsnorm_kernel(const float* __restrict__ x,
                                                      const float* __restrict__ w,
                                                      void* __restrict__ out) {
    int row = blockIdx.x;
    const float4* xr = (const float4*)(x + (size_t)row * D_);
    float ss = 0.f;
    for (int i = threadIdx.x; i < D_/4; i += 256) {
        float4 v = xr[i];
        ss += v.x*v.x + v.y*v.y + v.z*v.z + v.w*v.w;
    }
    __shared__ float red[4];
    for (int off = 32; off; off >>= 1) ss += __shfl_down(ss, off);
    if ((threadIdx.x & 63) == 0) red[threadIdx.x >> 6] = ss;
    __syncthreads();
    float tot = red[0] + red[1] + red[2] + red[3];
    float scale = rsqrtf(tot / (float)D_ + 1e-5f);
    const float4* w4 = (const float4*)w;
    for (int i = threadIdx.x; i < D_/4; i += 256) {
        float4 v = xr[i], g = w4[i];
        float a = v.x*scale*g.x, b = v.y*scale*g.y, c = v.z*scale*g.z, d = v.w*scale*g.w;
        if (OUTBF) {
            ushort4 o; o.x = f2bf(a); o.y = f2bf(b); o.z = f2bf(c); o.w = f2bf(d);
            ((ushort4*)((u16*)out + (size_t)row * D_))[i] = o;
        } else {
            float4 o; o.x = a; o.y = b; o.z = c; o.w = d;
            ((float4*)((float*)out + (size_t)row * D_))[i] = o;
        }
    }
}

// ------------------------------------------------------------------
// transpose + f32->bf16: in [K][N] f32 row-major  ->  out [N][K] bf16 row-major
__global__ __launch_bounds__(256) void convt_kernel(const float* __restrict__ in,
                                                    u16* __restrict__ outT,
                                                    int K, int N) {
    __shared__ float tile[32][33];
    int k0 = blockIdx.y * 32, n0 = blockIdx.x * 32;
    int t = threadIdx.x;
    int r = t >> 3, c4 = (t & 7) * 4;
    float4 v = *(const float4*)(in + (size_t)(k0 + r) * N + n0 + c4);
    tile[r][c4] = v.x; tile[r][c4+1] = v.y; tile[r][c4+2] = v.z; tile[r][c4+3] = v.w;
    __syncthreads();
    int n = t >> 3, kc = (t & 7) * 4;
    ushort4 o;
    o.x = f2bf(tile[kc][n]);   o.y = f2bf(tile[kc+1][n]);
    o.z = f2bf(tile[kc+2][n]); o.w = f2bf(tile[kc+3][n]);
    *(ushort4*)(outT + (size_t)(n0 + n) * K + k0 + kc) = o;
}

// convt with G/U interleave: output row n -> W' row (n/128)*256 + SLOT*128 + n%128
template<int SLOT>
__global__ __launch_bounds__(256) void convt_gu(const float* __restrict__ in,
                                                u16* __restrict__ outT,
                                                int K, int N) {
    __shared__ float tile[32][33];
    int k0 = blockIdx.y * 32, n0 = blockIdx.x * 32;
    int t = threadIdx.x;
    int r = t >> 3, c4 = (t & 7) * 4;
    float4 v = *(const float4*)(in + (size_t)(k0 + r) * N + n0 + c4);
    tile[r][c4] = v.x; tile[r][c4+1] = v.y; tile[r][c4+2] = v.z; tile[r][c4+3] = v.w;
    __syncthreads();
    int n = t >> 3, kc = (t & 7) * 4;
    ushort4 o;
    o.x = f2bf(tile[kc][n]);   o.y = f2bf(tile[kc+1][n]);
    o.z = f2bf(tile[kc+2][n]); o.w = f2bf(tile[kc+3][n]);
    int orow = n0 + n;
    int wrow = ((orow >> 7) << 8) + SLOT * 128 + (orow & 127);
    *(ushort4*)(outT + (size_t)wrow * K + k0 + kc) = o;
}

// ------------------------------------------------------------------
// MFMA GEMM, B transposed: C[M,N] (+)= A[M,K](bf16) @ Bt[N,K](bf16)^T, C f32
template<int ACC>
__global__ __launch_bounds__(256) void gemm_bt(const u16* __restrict__ A,
                                               const u16* __restrict__ Bt,
                                               float* __restrict__ C,
                                               int N, int K) {
    __shared__ __align__(16) u16 As[128*64];
    __shared__ __align__(16) u16 Bs[128*64];
    int tid = threadIdx.x, lane = tid & 63;
    int wid = tid >> 6, wm = wid >> 1, wn = wid & 1;
    int m0 = blockIdx.y * 128, n0 = blockIdx.x * 128;
    const u16* Ab = A  + (size_t)m0 * K;
    const u16* Bb = Bt + (size_t)n0 * K;
    f32x4 acc[4][4] = {};
    for (int k0 = 0; k0 < K; k0 += 64) {
        #pragma unroll
        for (int qq = 0; qq < 4; qq++) {
            int u = qq * 256 + tid;
            int row = u >> 3, cu = u & 7, scu = cu ^ (row & 7);
            size_t goff = (size_t)row * K + k0 + scu * 8;
            gload16(Ab + goff, (char*)As + u * 16);
            gload16(Bb + goff, (char*)Bs + u * 16);
        }
        __syncthreads();
        #pragma unroll
        for (int kk = 0; kk < 2; kk++) {
            int cu = kk * 4 + (lane >> 4);
            bf16x8 af[4], bfr[4];
            #pragma unroll
            for (int i = 0; i < 4; i++) {
                int ar = wm * 64 + i * 16 + (lane & 15);
                af[i]  = *(const bf16x8*)((const char*)As + (((ar << 3) | (cu ^ (ar & 7))) << 4));
                int br = wn * 64 + i * 16 + (lane & 15);
                bfr[i] = *(const bf16x8*)((const char*)Bs + (((br << 3) | (cu ^ (br & 7))) << 4));
            }
            #pragma unroll
            for (int i = 0; i < 4; i++)
                #pragma unroll
                for (int j = 0; j < 4; j++)
                    acc[i][j] = __builtin_amdgcn_mfma_f32_16x16x32_bf16(af[i], bfr[j], acc[i][j], 0, 0, 0);
        }
        __syncthreads();
    }
    int r0 = (lane >> 4) * 4, c0 = lane & 15;
    #pragma unroll
    for (int i = 0; i < 4; i++)
        #pragma unroll
        for (int j = 0; j < 4; j++) {
            int row = m0 + wm * 64 + i * 16 + r0;
            int col = n0 + wn * 64 + j * 16 + c0;
            float* cp = C + (size_t)row * N + col;
            #pragma unroll
            for (int r = 0; r < 4; r++) {
                if (ACC) cp[(size_t)r * N] += acc[i][j][r];
                else     cp[(size_t)r * N] = acc[i][j][r];
            }
        }
}

// ------------------------------------------------------------------
// 256x256-tile fused gate/up GEMM over interleaved W' [16384][2048].
// 512 thr = 8 waves (2M x 4N), wave tile 128x64. Double-buffered LDS,
// counted vmcnt(8) (never drains in-loop), setprio around MFMA clusters.
// Epilogue: U-waves (wn>=2) hand acc to G-waves via LDS; silu(g)*u -> bf16.
__global__ __launch_bounds__(512) void gemm_gateup8(const u16* __restrict__ A,
                                                    const u16* __restrict__ Wt,
                                                    u16* __restrict__ act,
                                                    int Nact, int K) {
    __shared__ __align__(16) u16 lds[2][2][256 * 64];   // 128 KiB
    int tid = threadIdx.x, lane = tid & 63;
    int w = tid >> 6;
    int wm = w >> 2, wn = w & 3;
    int g = lane >> 4, li = lane & 15;
    int m0 = blockIdx.y * 256, n0 = blockIdx.x * 256;   // n0 in W' space
    const u16* Ab = A  + (size_t)m0 * K;
    const u16* Bb = Wt + (size_t)n0 * K;
    int nt = K >> 6;

    f32x4 acc[8][4] = {};

    // stage K-tile t into buffer (t&1): 8 gload16 per thread
    #define STAGE8(t)                                                              \
        do {                                                                       \
            int p_ = (t) & 1;                                                      \
            int kb_ = (t) << 6;                                                    \
            _Pragma("unroll")                                                      \
            for (int q_ = 0; q_ < 4; q_++) {                                       \
                int u_ = q_ * 512 + tid;                                           \
                int row_ = u_ >> 3, c_ = u_ & 7;                                   \
                int sc_ = c_ ^ (row_ & 7);                                         \
                gload16(Ab + (size_t)row_ * K + kb_ + sc_ * 8,                     \
                        (char*)&lds[p_][0][0] + u_ * 16);                          \
                gload16(Bb + (size_t)row_ * K + kb_ + sc_ * 8,                     \
                        (char*)&lds[p_][1][0] + u_ * 16);                          \
            }                                                                      \
        } while (0)

    STAGE8(0);
    STAGE8(1);

    for (int t = 0; t < nt; t++) {
        int p = t & 1;
        if (t + 1 < nt) { asm volatile("s_waitcnt vmcnt(8)" ::: "memory"); }
        else            { asm volatile("s_waitcnt vmcnt(0)" ::: "memory"); }
        __builtin_amdgcn_s_barrier();
        __builtin_amdgcn_sched_barrier(0);

        // B fragments for the whole tile (held in regs)
        bf16x8 bfr[4][2];
        #pragma unroll
        for (int j = 0; j < 4; j++)
            #pragma unroll
            for (int ks = 0; ks < 2; ks++) {
                int br = wn * 64 + j * 16 + li;
                int cu = ks * 4 + g;
                bfr[j][ks] = *(const bf16x8*)((const char*)&lds[p][1][0] +
                                              (((br << 3) | (cu ^ (br & 7))) << 4));
            }
        // 4 quadrant phases: 4 A-reads + 16 MFMA each
        #pragma unroll
        for (int q = 0; q < 4; q++) {
            bf16x8 af[2][2];
            #pragma unroll
            for (int i = 0; i < 2; i++)
                #pragma unroll
                for (int ks = 0; ks < 2; ks++) {
                    int ar = wm * 128 + q * 32 + i * 16 + li;
                    int cu = ks * 4 + g;
                    af[i][ks] = *(const bf16x8*)((const char*)&lds[p][0][0] +
                                                 (((ar << 3) | (cu ^ (ar & 7))) << 4));
                }
            __builtin_amdgcn_s_setprio(1);
            #pragma unroll
            for (int i = 0; i < 2; i++)
                #pragma unroll
                for (int j = 0; j < 4; j++)
                    #pragma unroll
                    for (int ks = 0; ks < 2; ks++)
                        acc[q * 2 + i][j] = __builtin_amdgcn_mfma_f32_16x16x32_bf16(
                            af[i][ks], bfr[j][ks], acc[q * 2 + i][j], 0, 0, 0);
            __builtin_amdgcn_s_setprio(0);
        }
        __builtin_amdgcn_s_barrier();
        __builtin_amdgcn_sched_barrier(0);
        if (t + 2 < nt) STAGE8(t + 2);
    }
    #undef STAGE8

    // ---- epilogue: U-waves dump acc to LDS, G-waves fuse silu(g)*u ----
    __syncthreads();
    float* X = (float*)&lds[0][0][0];    // 128 KiB = 4 regions x 128x64 f32
    if (wn >= 2) {
        float* Rr = X + (size_t)(wm * 2 + (wn - 2)) * 8192;
        #pragma unroll
        for (int i = 0; i < 8; i++)
            #pragma unroll
            for (int j = 0; j < 4; j++)
                #pragma unroll
                for (int r = 0; r < 4; r++) {
                    int row = i * 16 + g * 4 + r;
                    int col = j * 16 + li;
                    Rr[row * 64 + (col ^ (((row >> 2) & 3) << 4))] = acc[i][j][r];
                }
    }
    __syncthreads();
    if (wn < 2) {
        const float* Rr = X + (size_t)(wm * 2 + wn) * 8192;
        int colbase = (n0 >> 1) + wn * 64;
        #pragma unroll
        for (int i = 0; i < 8; i++)
            #pragma unroll
            for (int j = 0; j < 4; j++)
                #pragma unroll
                for (int r = 0; r < 4; r++) {
                    int row = i * 16 + g * 4 + r;
                    int col = j * 16 + li;
                    float gv = acc[i][j][r];
                    float uv = Rr[row * 64 + (col ^ (((row >> 2) & 3) << 4))];
                    float s = gv / (1.f + __expf(-gv));
                    act[(size_t)(m0 + wm * 128 + row) * Nact + colbase + col] = f2bf(s * uv);
                }
    }
}

// ------------------------------------------------------------------
// LoRA
__global__ __launch_bounds__(256) void lora_a_kernel(const u16* __restrict__ h,
                                                     const float* __restrict__ la,
                                                     float* __restrict__ t16) {
    int r = threadIdx.x >> 4;
    int c = threadIdx.x & 15;
    int row = blockIdx.x * 16 + r;
    const ushort4* hr = (const ushort4*)(h + (size_t)row * D_);
    const float4* lr = (const float4*)(la + (size_t)c * D_);
    float acc = 0.f;
    #pragma unroll 4
    for (int i = 0; i < D_/4; i++) {
        ushort4 a = hr[i]; float4 b = lr[i];
        acc += bf2f(a.x)*b.x + bf2f(a.y)*b.y + bf2f(a.z)*b.z + bf2f(a.w)*b.w;
    }
    t16[(size_t)row * R_ + c] = acc;
}

__global__ __launch_bounds__(256) void lora_b_kernel(const float* __restrict__ t16,
                                                     const float* __restrict__ lb,
                                                     float* __restrict__ out, int N) {
    int row = blockIdx.x;
    __shared__ float ts[R_];
    if (threadIdx.x < R_) ts[threadIdx.x] = t16[(size_t)row * R_ + threadIdx.x];
    __syncthreads();
    for (int d = threadIdx.x; d < N; d += 256) {
        const float4* lbr = (const float4*)(lb + (size_t)d * R_);
        float acc = 0.f;
        #pragma unroll
        for (int r4 = 0; r4 < 4; r4++) {
            float4 v = lbr[r4];
            acc += v.x*ts[r4*4] + v.y*ts[r4*4+1] + v.z*ts[r4*4+2] + v.w*ts[r4*4+3];
        }
        out[(size_t)row * N + d] += 2.0f * acc;
    }
}

// ------------------------------------------------------------------
// fused RoPE + f32->bf16 conv, Q: [BS,H,128] f32 -> Qc [B][H][S][128] bf16
__global__ void qconv_rope(const float* __restrict__ q, u16* __restrict__ Qc) {
    int tok = blockIdx.x, h = blockIdx.y, t = threadIdx.x;   // t: 0..63
    int b = tok >> 10, s = tok & (S_ - 1);
    float inv = __expf(-(float)t * (13.122363377404328f / 64.0f));
    float f = (float)s * inv;
    float c = __cosf(f), si = __sinf(f);
    const float* src = q + ((size_t)tok * H_ + h) * HD_;
    float x0 = src[t], x1 = src[t + 64];
    u16* dst = Qc + (((size_t)(b * H_ + h)) * S_ + s) * HD_;
    dst[t]      = f2bf(x0 * c - x1 * si);
    dst[t + 64] = f2bf(x1 * c + x0 * si);
}

// K: [BS,KV,128] f32 -> Kc [B][KV][S][128] bf16 (with RoPE)
__global__ void kconv_rope(const float* __restrict__ k, u16* __restrict__ Kc) {
    int tok = blockIdx.x, h = blockIdx.y, t = threadIdx.x;
    int b = tok >> 10, s = tok & (S_ - 1);
    float inv = __expf(-(float)t * (13.122363377404328f / 64.0f));
    float f = (float)s * inv;
    float c = __cosf(f), si = __sinf(f);
    const float* src = k + ((size_t)tok * KV_ + h) * HD_;
    float x0 = src[t], x1 = src[t + 64];
    u16* dst = Kc + (((size_t)(b * KV_ + h)) * S_ + s) * HD_;
    dst[t]      = f2bf(x0 * c - x1 * si);
    dst[t + 64] = f2bf(x1 * c + x0 * si);
}

// V: [BS,KV,128] f32 -> Vt [B][KV][128][S] bf16 (transposed)
__global__ __launch_bounds__(256) void vconv_t(const float* __restrict__ vb,
                                               u16* __restrict__ Vt) {
    __shared__ float tile[32][33];
    int s0 = blockIdx.x * 32, d0 = blockIdx.y * 32;
    int bk = blockIdx.z;
    int b = bk >> 2, kvh = bk & 3;
    int t = threadIdx.x;
    int r = t >> 3, c4 = (t & 7) * 4;
    float4 v = *(const float4*)(vb + (((size_t)(b * S_ + s0 + r)) * KV_ + kvh) * HD_ + d0 + c4);
    tile[r][c4] = v.x; tile[r][c4+1] = v.y; tile[r][c4+2] = v.z; tile[r][c4+3] = v.w;
    __syncthreads();
    int dr = t >> 3, s4 = (t & 7) * 4;
    ushort4 o;
    o.x = f2bf(tile[s4][dr]);   o.y = f2bf(tile[s4+1][dr]);
    o.z = f2bf(tile[s4+2][dr]); o.w = f2bf(tile[s4+3][dr]);
    *(ushort4*)(Vt + (((size_t)(b * KV_ + kvh)) * HD_ + d0 + dr) * S_ + s0 + s4) = o;
}

// ------------------------------------------------------------------
// flash attention v3: block = (32-row q-tile, kv-head, batch), 8 waves =
// 4 q-heads x 2 q-subtiles sharing one K/V LDS staging (GQA amortization).
__global__ __launch_bounds__(512) void flash_attn(const u16* __restrict__ Qc,
                                                  const u16* __restrict__ Kc,
                                                  const u16* __restrict__ Vt,
                                                  const int* __restrict__ am,
                                                  u16* __restrict__ o) {
    __shared__ __align__(16) u16 Ks[64 * 128];     // [k-row][d], swizzled 16B chunks
    __shared__ __align__(16) u16 Vs[128 * 64];     // [d-row][k], swizzled
    __shared__ __align__(16) u16 Ps[8][16][72];    // per-wave P, padded rows
    __shared__ int am_s[KBLK];
    int qt = blockIdx.x, kvh = blockIdx.y, b = blockIdx.z;
    int tid = threadIdx.x, lane = tid & 63, w = tid >> 6;
    int g = lane >> 4, li = lane & 15;
    int h = kvh * 4 + (w & 3);
    int qrow0 = qt * QT2 + (w >> 2) * 16;          // wave's 16-row q-frag base

    bf16x8 qf[4];
    const u16* qb = Qc + (((size_t)(b * H_ + h)) * S_ + qrow0 + li) * HD_;
    #pragma unroll
    for (int dd = 0; dd < 4; dd++) qf[dd] = *(const bf16x8*)(qb + dd * 32 + g * 8);

    float m_r[4], l_r[4];
    f32x4 oacc[8];
    #pragma unroll
    for (int r = 0; r < 4; r++) { m_r[r] = -1e30f; l_r[r] = 0.f; }
    #pragma unroll
    for (int d = 0; d < 8; d++) oacc[d] = (f32x4){0.f, 0.f, 0.f, 0.f};

    const u16* Kg = Kc + ((size_t)(b * KV_ + kvh)) * S_ * HD_;
    const u16* Vg = Vt + ((size_t)(b * KV_ + kvh)) * HD_ * S_;
    int qg0 = qrow0 + g * 4;
    int nkv = (qt * QT2 + QT2 - 1) >> 6;           // last kv-tile index

    for (int kvt = 0; kvt <= nkv; kvt++) {
        int kv0 = kvt * KBLK;
        #pragma unroll
        for (int qq = 0; qq < 2; qq++) {
            int u = qq * 512 + tid;
            int krow = u >> 4, p = u & 15;
            gload16(Kg + (size_t)(kv0 + krow) * HD_ + (p ^ (krow & 7)) * 8, (char*)Ks + u * 16);
            int vrow = u >> 3, pv = u & 7;
            gload16(Vg + (size_t)vrow * S_ + kv0 + (pv ^ (vrow & 7)) * 8, (char*)Vs + u * 16);
        }
        if (tid < KBLK) am_s[tid] = am[b * S_ + kv0 + tid];
        __syncthreads();

        if (kv0 <= qrow0 + 15) {
            float ps[4][4];
            #pragma unroll
            for (int kt = 0; kt < 4; kt++) {
                f32x4 sa = (f32x4){0.f, 0.f, 0.f, 0.f};
                int row = kt * 16 + li;
                #pragma unroll
                for (int dd = 0; dd < 4; dd++) {
                    int c = dd * 4 + g;
                    bf16x8 kf = *(const bf16x8*)((const char*)Ks + ((row * 16 + (c ^ (row & 7))) << 4));
                    sa = __builtin_amdgcn_mfma_f32_16x16x32_bf16(qf[dd], kf, sa, 0, 0, 0);
                }
                int kcol = kv0 + kt * 16 + li;
                int amok = am_s[kt * 16 + li];
                #pragma unroll
                for (int r = 0; r < 4; r++) {
                    float s = sa[r] * 0.08838834764831845f;
                    ps[kt][r] = (amok && kcol <= qg0 + r) ? s : -1e9f;
                }
            }

            float rmax[4], rsum[4], scl[4];
            #pragma unroll
            for (int r = 0; r < 4; r++)
                rmax[r] = fmaxf(fmaxf(ps[0][r], ps[1][r]), fmaxf(ps[2][r], ps[3][r]));
            #pragma unroll
            for (int msk = 1; msk < 16; msk <<= 1)
                #pragma unroll
                for (int r = 0; r < 4; r++) rmax[r] = fmaxf(rmax[r], __shfl_xor(rmax[r], msk));
            #pragma unroll
            for (int r = 0; r < 4; r++) {
                float mn = fmaxf(m_r[r], rmax[r]);
                scl[r] = __expf(m_r[r] - mn);
                m_r[r] = mn;
                rsum[r] = 0.f;
            }
            #pragma unroll
            for (int kt = 0; kt < 4; kt++)
                #pragma unroll
                for (int r = 0; r < 4; r++) {
                    float p = __expf(ps[kt][r] - m_r[r]);
                    ps[kt][r] = p;
                    rsum[r] += p;
                }
            #pragma unroll
            for (int msk = 1; msk < 16; msk <<= 1)
                #pragma unroll
                for (int r = 0; r < 4; r++) rsum[r] += __shfl_xor(rsum[r], msk);
            #pragma unroll
            for (int r = 0; r < 4; r++) l_r[r] = l_r[r] * scl[r] + rsum[r];
            #pragma unroll
            for (int d = 0; d < 8; d++)
                #pragma unroll
                for (int r = 0; r < 4; r++) oacc[d][r] *= scl[r];

            #pragma unroll
            for (int kt = 0; kt < 4; kt++)
                #pragma unroll
                for (int r = 0; r < 4; r++)
                    Ps[w][g * 4 + r][kt * 16 + li] = f2bf(ps[kt][r]);
            bf16x8 pf[2];
            #pragma unroll
            for (int ks = 0; ks < 2; ks++)
                pf[ks] = *(const bf16x8*)&Ps[w][li][ks * 32 + g * 8];

            #pragma unroll
            for (int dblk = 0; dblk < 8; dblk++) {
                int row = dblk * 16 + li;
                #pragma unroll
                for (int ks = 0; ks < 2; ks++) {
                    int c = ks * 4 + g;
                    bf16x8 vf = *(const bf16x8*)((const char*)Vs + ((row * 8 + (c ^ (row & 7))) << 4));
                    oacc[dblk] = __builtin_amdgcn_mfma_f32_16x16x32_bf16(pf[ks], vf, oacc[dblk], 0, 0, 0);
                }
            }
        }
        __syncthreads();
    }

    float invl[4];
    #pragma unroll
    for (int r = 0; r < 4; r++) invl[r] = 1.f / l_r[r];
    #pragma unroll
    for (int dblk = 0; dblk < 8; dblk++)
        #pragma unroll
        for (int r = 0; r < 4; r++) {
            int qrow = qg0 + r;
            o[(((size_t)b * S_ + qrow) * H_ + h) * HD_ + dblk * 16 + li] =
                f2bf(oacc[dblk][r] * invl[r]);
        }
}

// ------------------------------------------------------------------
__global__ __launch_bounds__(256) void pool_kernel(const float* __restrict__ h,
                                                   const int* __restrict__ am,
                                                   float* __restrict__ out) {
    int b = blockIdx.y;
    int d = blockIdx.x * 256 + threadIdx.x;
    float acc = 0.f, ms = 0.f;
    for (int s = 0; s < S_; s++) {
        float mm = (float)am[b * S_ + s];
        ms  += mm;
        acc += mm * h[((size_t)b * S_ + s) * D_ + d];
    }
    out[(size_t)b * D_ + d] = acc / fmaxf(ms, 1e-9f);
}

// ------------------------------------------------------------------
extern "C" void kernel_launch(void* const* d_in, const int* in_sizes, int n_in,
                              void* d_out, int out_size, void* d_ws, size_t ws_size,
                              hipStream_t stream) {
    const float* embed = (const float*)d_in[0];
    const float* wq    = (const float*)d_in[1];
    const float* wk    = (const float*)d_in[2];
    const float* wv    = (const float*)d_in[3];
    const float* wo    = (const float*)d_in[4];
    const float* laq   = (const float*)d_in[5];
    const float* lbq   = (const float*)d_in[6];
    const float* lav   = (const float*)d_in[7];
    const float* lbv   = (const float*)d_in[8];
    const float* wg    = (const float*)d_in[9];
    const float* wu    = (const float*)d_in[10];
    const float* wd    = (const float*)d_in[11];
    const float* n1    = (const float*)d_in[12];
    const float* n2    = (const float*)d_in[13];
    const float* nf    = (const float*)d_in[14];
    const int*   ids   = (const int*)d_in[15];
    const int*   am    = (const int*)d_in[16];
    float* out = (float*)d_out;

    char* base = (char*)d_ws;
    float* x   = (float*)base;                          // 33.55 MB f32
    u16*   hbf = (u16*)(base + 33554432);               // 16.78 MB bf16
    u16*   obf = (u16*)(base + 50331648);               // 16.78 MB bf16
    char*  Rg  = base + 67108864;                       // 67.11 MB multi-purpose
    float* q   = (float*)Rg;                            // 33.55 MB f32
    float* kb  = (float*)(Rg + 33554432);               // 8.39 MB f32
    float* vb  = (float*)(Rg + 41943040);               // 8.39 MB f32
    u16*   act = (u16*)Rg;                              // 67.11 MB bf16 (after attn)
    float* hf  = (float*)Rg;                            // final norm f32 (after MLP)
    float* t16 = (float*)(base + 134217728);            // 0.26 MB
    u16*   wT0 = (u16*)(base + 134479872);              // 64 MB as W' (or 33.55 MB)
    u16*   Qc  = (u16*)(base + 201588736);              // 16.78 MB bf16
    u16*   Kc  = (u16*)(base + 218365952);              // 4.19 MB bf16
    u16*   Vtb = (u16*)(base + 222560256);              // 4.19 MB bf16
    // total ~226.8 MB

    embed_kernel<<<BS_, 256, 0, stream>>>(embed, ids, x);

    for (int l = 0; l < NL_; l++) {
        const float* wql = wq + (size_t)l * D_ * D_;
        const float* wkl = wk + (size_t)l * D_ * (KV_*HD_);
        const float* wvl = wv + (size_t)l * D_ * (KV_*HD_);
        const float* wol = wo + (size_t)l * D_ * D_;
        const float* wgl = wg + (size_t)l * D_ * F_;
        const float* wul = wu + (size_t)l * D_ * F_;
        const float* wdl = wd + (size_t)l * F_ * D_;

        rmsnorm_kernel<1><<<BS_, 256, 0, stream>>>(x, n1 + (size_t)l * D_, hbf);

        // q projection
        convt_kernel<<<dim3(D_/32, D_/32), 256, 0, stream>>>(wql, wT0, D_, D_);
        gemm_bt<0><<<dim3(D_/128, BS_/128), 256, 0, stream>>>(hbf, wT0, q, D_, D_);
        lora_a_kernel<<<BS_/16, 256, 0, stream>>>(hbf, laq + (size_t)l * R_ * D_, t16);
        lora_b_kernel<<<BS_, 256, 0, stream>>>(t16, lbq + (size_t)l * D_ * R_, q, D_);

        // k, v projections
        convt_kernel<<<dim3((KV_*HD_)/32, D_/32), 256, 0, stream>>>(wkl, wT0, D_, KV_*HD_);
        gemm_bt<0><<<dim3((KV_*HD_)/128, BS_/128), 256, 0, stream>>>(hbf, wT0, kb, KV_*HD_, D_);
        convt_kernel<<<dim3((KV_*HD_)/32, D_/32), 256, 0, stream>>>(wvl, wT0, D_, KV_*HD_);
        gemm_bt<0><<<dim3((KV_*HD_)/128, BS_/128), 256, 0, stream>>>(hbf, wT0, vb, KV_*HD_, D_);
        lora_a_kernel<<<BS_/16, 256, 0, stream>>>(hbf, lav + (size_t)l * R_ * D_, t16);
        lora_b_kernel<<<BS_, 256, 0, stream>>>(t16, lbv + (size_t)l * (KV_*HD_) * R_, vb, KV_*HD_);

        // RoPE + layout conversion for attention
        qconv_rope<<<dim3(BS_, H_),  64, 0, stream>>>(q,  Qc);
        kconv_rope<<<dim3(BS_, KV_), 64, 0, stream>>>(kb, Kc);
        vconv_t<<<dim3(S_/32, HD_/32, B_*KV_), 256, 0, stream>>>(vb, Vtb);

        flash_attn<<<dim3(S_/QT2, KV_, B_), 512, 0, stream>>>(Qc, Kc, Vtb, am, obf);

        // o projection (accumulate into residual x)
        convt_kernel<<<dim3(D_/32, D_/32), 256, 0, stream>>>(wol, wT0, D_, D_);
        gemm_bt<1><<<dim3(D_/128, BS_/128), 256, 0, stream>>>(obf, wT0, x, D_, D_);

        // MLP: gate/up interleaved into W' [16384][2048], 256^2 pipelined GEMM
        rmsnorm_kernel<1><<<BS_, 256, 0, stream>>>(x, n2 + (size_t)l * D_, hbf);
        convt_gu<0><<<dim3(F_/32, D_/32), 256, 0, stream>>>(wgl, wT0, D_, F_);
        convt_gu<1><<<dim3(F_/32, D_/32), 256, 0, stream>>>(wul, wT0, D_, F_);
        gemm_gateup8<<<dim3((2*F_)/256, BS_/256), 512, 0, stream>>>(hbf, wT0, act, F_, D_);
        convt_kernel<<<dim3(D_/32, F_/32), 256, 0, stream>>>(wdl, wT0, F_, D_);
        gemm_bt<1><<<dim3(D_/128, BS_/128), 256, 0, stream>>>(act, wT0, x, D_, F_);
    }

    rmsnorm_kernel<0><<<BS_, 256, 0, stream>>>(x, nf, hf);
    pool_kernel<<<dim3(D_/256, B_), 256, 0, stream>>>(hf, am, out);
}